// Round 1
// baseline (8120.320 us; speedup 1.0000x reference)
//
#include <hip/hip_runtime.h>
#include <stdint.h>

#define B_TOK 32768
#define DIM   1024
#define NEXP  8
#define NFR   4
#define HF    2048
#define HS    4096
#define CHUNK 8192

typedef __bf16 bf16;
typedef bf16  bf16x8 __attribute__((ext_vector_type(8)));
typedef bf16  bf16x4 __attribute__((ext_vector_type(4)));
typedef float f32x4  __attribute__((ext_vector_type(4)));

// ---------------------------------------------------------------------------
// Gating + RMS + x->bf16, one pass over x. One wave per row.
// comb[row*8+e] = renormalized top-2 softmax weight (0 if unselected).
// rms[row] = rsqrt(mean(x^2)+eps).  xb = bf16(x).
// Gate dots in fp64 so the top-k ranking matches the numpy reference.
// ---------------------------------------------------------------------------
__global__ __launch_bounds__(256) void gate_kernel(
    const float* __restrict__ x, const float* __restrict__ gw_g,
    bf16* __restrict__ xb, float* __restrict__ rms, float* __restrict__ comb) {
  __shared__ float gw[NEXP * DIM];
  for (int i = threadIdx.x; i < NEXP * DIM; i += 256) gw[i] = gw_g[i];
  __syncthreads();
  const int lane = threadIdx.x & 63;
  const int wave = threadIdx.x >> 6;
  const int row  = blockIdx.x * 4 + wave;
  const float* xr = x + (size_t)row * DIM;
  float xv[16];
#pragma unroll
  for (int i = 0; i < 16; i++) xv[i] = xr[lane + 64 * i];
  float ss = 0.f;
  double dot[8] = {0, 0, 0, 0, 0, 0, 0, 0};
#pragma unroll
  for (int i = 0; i < 16; i++) {
    ss += xv[i] * xv[i];
    const int idx = lane + 64 * i;
#pragma unroll
    for (int e = 0; e < 8; e++) dot[e] += (double)xv[i] * (double)gw[e * DIM + idx];
  }
#pragma unroll
  for (int off = 32; off > 0; off >>= 1) {
    ss += __shfl_xor(ss, off, 64);
#pragma unroll
    for (int e = 0; e < 8; e++) dot[e] += __shfl_xor(dot[e], off, 64);
  }
  const float rv = 1.0f / sqrtf(ss * (1.0f / DIM) + 1e-6f);
  if (lane == 0) rms[row] = rv;
  int i1 = 0; double m1 = dot[0];
#pragma unroll
  for (int e = 1; e < 8; e++) if (dot[e] > m1) { m1 = dot[e]; i1 = e; }
  int i2 = 0; double m2 = -1e300;
#pragma unroll
  for (int e = 0; e < 8; e++) if (e != i1 && dot[e] > m2) { m2 = dot[e]; i2 = e; }
  const double t  = exp(m2 - m1);                 // softmax top2 renorm == 2-way softmax
  const float  c1 = (float)(1.0 / (1.0 + t));
  const float  c2 = (float)(t / (1.0 + t));
  if (lane < 8) comb[(size_t)row * 8 + lane] = (lane == i1) ? c1 : ((lane == i2) ? c2 : 0.0f);
#pragma unroll
  for (int i = 0; i < 16; i++) xb[(size_t)row * DIM + lane + 64 * i] = (bf16)xv[i];
}

// ---------------------------------------------------------------------------
// Weight conversion fp32 -> bf16 (optionally column-scaled by fr_norm[e][d]).
// ---------------------------------------------------------------------------
__global__ __launch_bounds__(256) void cvt_kernel(
    const float* __restrict__ src, bf16* __restrict__ dst, int n4) {
  const int i = blockIdx.x * 256 + threadIdx.x;
  if (i >= n4) return;
  f32x4 v = *(const f32x4*)(src + (size_t)i * 4);
  *(bf16x4*)(dst + (size_t)i * 4) = __builtin_convertvector(v, bf16x4);
}

__global__ __launch_bounds__(256) void cvt_scaled_kernel(
    const float* __restrict__ src, const float* __restrict__ norm,
    bf16* __restrict__ dst, int n4) {
  const int i = blockIdx.x * 256 + threadIdx.x;
  if (i >= n4) return;
  const size_t f = (size_t)i * 4;
  f32x4 v = *(const f32x4*)(src + f);
  const float* np_ = norm + ((f >> 21) << 10) + (f & 1023);  // [e][2048][1024] -> norm[e][d]
#pragma unroll
  for (int c = 0; c < 4; c++) v[c] *= np_[c];
  *(bf16x4*)(dst + f) = __builtin_convertvector(v, bf16x4);
}

// ---------------------------------------------------------------------------
// Stage a 128x64 bf16 tile (row-major, no pad) into LDS via global_load_lds.
// Per wave: 4 insts x 64 lanes x 16B = 4KB.  LDS dest is wave-uniform base.
// ---------------------------------------------------------------------------
__device__ __forceinline__ void stage64(const bf16* __restrict__ g0, int ld,
                                        bf16* s0, int wave, int lane) {
  const bf16* g = g0 + (size_t)(wave * 32 + (lane >> 3)) * ld + (lane & 7) * 8;
  bf16* s = s0 + wave * 2048;
#pragma unroll
  for (int i = 0; i < 4; i++) {
    __builtin_amdgcn_global_load_lds(
        (const __attribute__((address_space(1))) void*)(uintptr_t)(g + (size_t)(i * 8) * ld),
        (__attribute__((address_space(3))) void*)(uintptr_t)(s + i * 512), 16, 0, 0);
  }
}

// ---------------------------------------------------------------------------
// GEMM1 (dual-B): H1 = A@B1^T, H3 = A@B3^T;  G = silu(s*H1)*(s*H3) in bf16.
// A [M x K] bf16 rm, B1/B3 [N x K] bf16 rm (torch Linear layout), s = rms[row]
// (nullptr -> 1).  128x128 tile, BK=64, 4 waves of 64x64, 16x16x32 MFMA.
// ---------------------------------------------------------------------------
__global__ __launch_bounds__(256, 2) void gemm1_kernel(
    const bf16* __restrict__ A, const bf16* __restrict__ B1,
    const bf16* __restrict__ B3, const float* __restrict__ rms,
    bf16* __restrict__ G, int N, int K) {
  __shared__ __attribute__((aligned(16))) bf16 As[128 * 64];
  __shared__ __attribute__((aligned(16))) bf16 Bs1[128 * 64];
  __shared__ __attribute__((aligned(16))) bf16 Bs3[128 * 64];
  const int lane = threadIdx.x & 63, wave = threadIdx.x >> 6;
  const int wm = wave >> 1, wn = wave & 1;
  const int m0 = blockIdx.y * 128, n0 = blockIdx.x * 128;
  f32x4 acc1[4][4], acc3[4][4];
#pragma unroll
  for (int i = 0; i < 4; i++)
#pragma unroll
    for (int j = 0; j < 4; j++) {
      f32x4 z = {0.f, 0.f, 0.f, 0.f};
      acc1[i][j] = z; acc3[i][j] = z;
    }
  const bf16* Ab  = A  + (size_t)m0 * K;
  const bf16* B1b = B1 + (size_t)n0 * K;
  const bf16* B3b = B3 + (size_t)n0 * K;
  const int lr = lane & 15, lq = lane >> 4;
  for (int k0 = 0; k0 < K; k0 += 64) {
    stage64(Ab + k0, K, As, wave, lane);
    stage64(B1b + k0, K, Bs1, wave, lane);
    stage64(B3b + k0, K, Bs3, wave, lane);
    __syncthreads();
#pragma unroll
    for (int ks = 0; ks < 2; ks++) {
      bf16x8 af[4], bf_[4], cf_[4];
#pragma unroll
      for (int mi = 0; mi < 4; mi++)
        af[mi] = *(const bf16x8*)(As + (wm * 64 + mi * 16 + lr) * 64 + ks * 32 + lq * 8);
#pragma unroll
      for (int ni = 0; ni < 4; ni++) {
        const int off = (wn * 64 + ni * 16 + lr) * 64 + ks * 32 + lq * 8;
        bf_[ni] = *(const bf16x8*)(Bs1 + off);
        cf_[ni] = *(const bf16x8*)(Bs3 + off);
      }
#pragma unroll
      for (int mi = 0; mi < 4; mi++)
#pragma unroll
        for (int ni = 0; ni < 4; ni++) {
          acc1[mi][ni] = __builtin_amdgcn_mfma_f32_16x16x32_bf16(af[mi], bf_[ni], acc1[mi][ni], 0, 0, 0);
          acc3[mi][ni] = __builtin_amdgcn_mfma_f32_16x16x32_bf16(af[mi], cf_[ni], acc3[mi][ni], 0, 0, 0);
        }
    }
    __syncthreads();
  }
  // epilogue: C/D layout col=lane&15, row=(lane>>4)*4+r   [m89/m91 verified]
#pragma unroll
  for (int mi = 0; mi < 4; mi++) {
#pragma unroll
    for (int r = 0; r < 4; r++) {
      const int row = m0 + wm * 64 + mi * 16 + lq * 4 + r;
      const float s = rms ? rms[row] : 1.0f;
#pragma unroll
      for (int ni = 0; ni < 4; ni++) {
        const int col = n0 + wn * 64 + ni * 16 + lr;
        const float h1 = acc1[mi][ni][r] * s;
        const float h3 = acc3[mi][ni][r] * s;
        const float g  = h1 / (1.0f + __expf(-h1)) * h3;
        G[(size_t)row * N + col] = (bf16)g;
      }
    }
  }
}

// ---------------------------------------------------------------------------
// GEMM2: Y = G @ W2^T (N=1024), fused epilogue:
//   fractal: out += cw*(gamma[n]*(rms[m]*x*norm[n] + Y) + x)
//   plain:   out += cw*Y
// ---------------------------------------------------------------------------
__global__ __launch_bounds__(256, 2) void gemm2_kernel(
    const bf16* __restrict__ A, const bf16* __restrict__ Bw,
    const float* __restrict__ comb, const float* __restrict__ rms,
    const float* __restrict__ gamma, const float* __restrict__ nrm,
    const float* __restrict__ x, float* __restrict__ out, int K, int isfr) {
  __shared__ __attribute__((aligned(16))) bf16 As[128 * 64];
  __shared__ __attribute__((aligned(16))) bf16 Bs[128 * 64];
  const int lane = threadIdx.x & 63, wave = threadIdx.x >> 6;
  const int wm = wave >> 1, wn = wave & 1;
  const int m0 = blockIdx.y * 128, n0 = blockIdx.x * 128;
  f32x4 acc[4][4];
#pragma unroll
  for (int i = 0; i < 4; i++)
#pragma unroll
    for (int j = 0; j < 4; j++) { f32x4 z = {0.f, 0.f, 0.f, 0.f}; acc[i][j] = z; }
  const bf16* Ab = A  + (size_t)m0 * K;
  const bf16* Bb = Bw + (size_t)n0 * K;
  const int lr = lane & 15, lq = lane >> 4;
  for (int k0 = 0; k0 < K; k0 += 64) {
    stage64(Ab + k0, K, As, wave, lane);
    stage64(Bb + k0, K, Bs, wave, lane);
    __syncthreads();
#pragma unroll
    for (int ks = 0; ks < 2; ks++) {
      bf16x8 af[4], bf_[4];
#pragma unroll
      for (int mi = 0; mi < 4; mi++)
        af[mi] = *(const bf16x8*)(As + (wm * 64 + mi * 16 + lr) * 64 + ks * 32 + lq * 8);
#pragma unroll
      for (int ni = 0; ni < 4; ni++)
        bf_[ni] = *(const bf16x8*)(Bs + (wn * 64 + ni * 16 + lr) * 64 + ks * 32 + lq * 8);
#pragma unroll
      for (int mi = 0; mi < 4; mi++)
#pragma unroll
        for (int ni = 0; ni < 4; ni++)
          acc[mi][ni] = __builtin_amdgcn_mfma_f32_16x16x32_bf16(af[mi], bf_[ni], acc[mi][ni], 0, 0, 0);
    }
    __syncthreads();
  }
#pragma unroll
  for (int mi = 0; mi < 4; mi++) {
#pragma unroll
    for (int r = 0; r < 4; r++) {
      const int row = m0 + wm * 64 + mi * 16 + lq * 4 + r;
      const float cw = comb[(size_t)row * 8];
#pragma unroll
      for (int ni = 0; ni < 4; ni++) {
        const int col = n0 + wn * 64 + ni * 16 + lr;
        const float a = acc[mi][ni][r];
        const size_t idx = (size_t)row * DIM + col;
        float res;
        if (isfr) {
          const float xvv = x[idx];
          res = cw * (gamma[col] * (rms[row] * xvv * nrm[col] + a) + xvv);
        } else {
          res = cw * a;
        }
        out[idx] += res;
      }
    }
  }
}

// ---------------------------------------------------------------------------
extern "C" void kernel_launch(void* const* d_in, const int* in_sizes, int n_in,
                              void* d_out, int out_size, void* d_ws, size_t ws_size,
                              hipStream_t stream) {
  const float* x        = (const float*)d_in[0];
  const float* gate_w   = (const float*)d_in[1];
  const float* fr_norm  = (const float*)d_in[2];
  const float* fr_gamma = (const float*)d_in[3];
  const float* fr_w1    = (const float*)d_in[4];
  const float* fr_w2    = (const float*)d_in[5];
  const float* fr_w3    = (const float*)d_in[6];
  const float* sw_w1    = (const float*)d_in[7];
  const float* sw_w2    = (const float*)d_in[8];
  const float* sw_w3    = (const float*)d_in[9];
  float* out = (float*)d_out;

  char* ws = (char*)d_ws;                       // ~273 MB used
  bf16*  xb   = (bf16*)(ws);                    // 64 MB  bf16(x)
  bf16*  fw1  = (bf16*)(ws + 67108864);         // 16 MB  fr_w1 * fr_norm
  bf16*  fw3  = (bf16*)(ws + 83886080);         // 16 MB  fr_w3 * fr_norm
  bf16*  fw2  = (bf16*)(ws + 100663296);        // 16 MB
  bf16*  s1b  = (bf16*)(ws + 117440512);        // 32 MB
  bf16*  s3b  = (bf16*)(ws + 150994944);        // 32 MB
  bf16*  s2b  = (bf16*)(ws + 184549376);        // 32 MB
  float* comb = (float*)(ws + 218103808);       // 1 MB
  float* rmsb = (float*)(ws + 219152384);       // 128 KB
  bf16*  G    = (bf16*)(ws + 219283456);        // 64 MB (CHUNK x HS bf16)

  hipMemsetAsync(d_out, 0, (size_t)out_size * sizeof(float), stream);
  gate_kernel<<<B_TOK / 4, 256, 0, stream>>>(x, gate_w, xb, rmsb, comb);
  cvt_scaled_kernel<<<8192, 256, 0, stream>>>(fr_w1, fr_norm, fw1, 2097152);
  cvt_scaled_kernel<<<8192, 256, 0, stream>>>(fr_w3, fr_norm, fw3, 2097152);
  cvt_kernel<<<8192, 256, 0, stream>>>(fr_w2, fw2, 2097152);
  cvt_kernel<<<16384, 256, 0, stream>>>(sw_w1, s1b, 4194304);
  cvt_kernel<<<16384, 256, 0, stream>>>(sw_w3, s3b, 4194304);
  cvt_kernel<<<16384, 256, 0, stream>>>(sw_w2, s2b, 4194304);

  for (int c = 0; c < B_TOK / CHUNK; c++) {
    const size_t r0 = (size_t)c * CHUNK;
    for (int e = 0; e < NEXP; e++) {
      if (e < NFR) {
        gemm1_kernel<<<dim3(HF / 128, CHUNK / 128), 256, 0, stream>>>(
            xb + r0 * DIM, fw1 + (size_t)e * HF * DIM, fw3 + (size_t)e * HF * DIM,
            rmsb + r0, G, HF, DIM);
        gemm2_kernel<<<dim3(DIM / 128, CHUNK / 128), 256, 0, stream>>>(
            G, fw2 + (size_t)e * DIM * HF, comb + r0 * 8 + e, rmsb + r0,
            fr_gamma + (size_t)e * DIM, fr_norm + (size_t)e * DIM,
            x + r0 * DIM, out + r0 * DIM, HF, 1);
      } else {
        const int j = e - NFR;
        gemm1_kernel<<<dim3(HS / 128, CHUNK / 128), 256, 0, stream>>>(
            xb + r0 * DIM, s1b + (size_t)j * HS * DIM, s3b + (size_t)j * HS * DIM,
            nullptr, G, HS, DIM);
        gemm2_kernel<<<dim3(DIM / 128, CHUNK / 128), 256, 0, stream>>>(
            G, s2b + (size_t)j * DIM * HS, comb + r0 * 8 + e, nullptr,
            nullptr, nullptr, nullptr, out + r0 * DIM, HS, 0);
      }
    }
  }
}

// Round 2
// 3817.167 us; speedup vs baseline: 2.1273x; 2.1273x over previous
//
#include <hip/hip_runtime.h>
#include <stdint.h>

#define B_TOK 32768
#define DIM   1024
#define NEXP  8
#define NFR   4
#define HF    2048
#define HS    4096
#define CT    64          // m-tiles per chunk (8192 gathered rows)
#define NCH   9           // chunks: 9*64=576 tiles >= worst case 520
#define PADROWS 66560     // 520 tiles * 128

typedef __bf16 bf16;
typedef bf16  bf16x8 __attribute__((ext_vector_type(8)));
typedef bf16  bf16x4 __attribute__((ext_vector_type(4)));
typedef float f32x4  __attribute__((ext_vector_type(4)));

// LDS tile layout: 128 rows x 64 bf16, 16B chunk cc of row R lives at
// elem offset R*64 + ((cc ^ (R&7))*8)   -- XOR swizzle kills the 16-way
// bank conflict of the unswizzled row-major layout while staying
// compatible with global_load_lds' contiguous wave-uniform dest.
#define LDSOFF(R, CC) (((R) << 6) + ((((CC) ^ ((R) & 7))) << 3))

// ---------------------------------------------------------------------------
// Gating + RMS + x->bf16. One wave per row. Writes top-2 ids + weights and
// histogram counts. Gate dots in fp64 so top-k ranking matches numpy ref.
// ---------------------------------------------------------------------------
__global__ __launch_bounds__(256) void gate_kernel(
    const float* __restrict__ x, const float* __restrict__ gw_g,
    bf16* __restrict__ xb, float* __restrict__ rms,
    int* __restrict__ top2, float* __restrict__ c12, int* __restrict__ cnt) {
  __shared__ float gw[NEXP * DIM];
  for (int i = threadIdx.x; i < NEXP * DIM; i += 256) gw[i] = gw_g[i];
  __syncthreads();
  const int lane = threadIdx.x & 63;
  const int wave = threadIdx.x >> 6;
  const int row  = blockIdx.x * 4 + wave;
  const float* xr = x + (size_t)row * DIM;
  float xv[16];
#pragma unroll
  for (int i = 0; i < 16; i++) xv[i] = xr[lane + 64 * i];
  float ss = 0.f;
  double dot[8] = {0, 0, 0, 0, 0, 0, 0, 0};
#pragma unroll
  for (int i = 0; i < 16; i++) {
    ss += xv[i] * xv[i];
    const int idx = lane + 64 * i;
#pragma unroll
    for (int e = 0; e < 8; e++) dot[e] += (double)xv[i] * (double)gw[e * DIM + idx];
  }
#pragma unroll
  for (int off = 32; off > 0; off >>= 1) {
    ss += __shfl_xor(ss, off, 64);
#pragma unroll
    for (int e = 0; e < 8; e++) dot[e] += __shfl_xor(dot[e], off, 64);
  }
  const float rv = 1.0f / sqrtf(ss * (1.0f / DIM) + 1e-6f);
  if (lane == 0) rms[row] = rv;
  int i1 = 0; double m1 = dot[0];
#pragma unroll
  for (int e = 1; e < 8; e++) if (dot[e] > m1) { m1 = dot[e]; i1 = e; }
  int i2 = 0; double m2 = -1e300;
#pragma unroll
  for (int e = 0; e < 8; e++) if (e != i1 && dot[e] > m2) { m2 = dot[e]; i2 = e; }
  const double t  = exp(m2 - m1);
  if (lane == 0) {
    top2[row] = i1 | (i2 << 8);
    c12[2 * row]     = (float)(1.0 / (1.0 + t));
    c12[2 * row + 1] = (float)(t / (1.0 + t));
    atomicAdd(&cnt[i1], 1);
    atomicAdd(&cnt[i2], 1);
  }
#pragma unroll
  for (int i = 0; i < 16; i++) xb[(size_t)row * DIM + lane + 64 * i] = (bf16)xv[i];
}

// ---------------------------------------------------------------------------
__global__ void offsets_kernel(const int* __restrict__ cnt,
                               int* __restrict__ tileOff, int* __restrict__ rowOff) {
  if (threadIdx.x == 0 && blockIdx.x == 0) {
    int t = 0;
    for (int e = 0; e < 8; e++) {
      tileOff[e] = t;
      rowOff[e]  = t * 128;
      t += (cnt[e] + 127) >> 7;
    }
    tileOff[8] = t;
  }
}

__global__ __launch_bounds__(256) void assign_kernel(
    const int* __restrict__ top2, const float* __restrict__ c12,
    const int* __restrict__ rowOff, int* __restrict__ cur,
    int* __restrict__ perm, float* __restrict__ cwg) {
  const int t = blockIdx.x * 256 + threadIdx.x;
  if (t >= B_TOK) return;
  const int pk = top2[t];
  const int e1 = pk & 255, e2 = pk >> 8;
  const int p1 = atomicAdd(&cur[e1], 1);
  const int g1 = rowOff[e1] + p1;
  perm[g1] = t; cwg[g1] = c12[2 * t];
  const int p2 = atomicAdd(&cur[e2], 1);
  const int g2 = rowOff[e2] + p2;
  perm[g2] = t; cwg[g2] = c12[2 * t + 1];
}

// ---------------------------------------------------------------------------
// Weight conversion fp32 -> bf16 (optionally column-scaled by fr_norm[e][d]).
// ---------------------------------------------------------------------------
__global__ __launch_bounds__(256) void cvt_kernel(
    const float* __restrict__ src, bf16* __restrict__ dst, int n4) {
  const int i = blockIdx.x * 256 + threadIdx.x;
  if (i >= n4) return;
  f32x4 v = *(const f32x4*)(src + (size_t)i * 4);
  *(bf16x4*)(dst + (size_t)i * 4) = __builtin_convertvector(v, bf16x4);
}

__global__ __launch_bounds__(256) void cvt_scaled_kernel(
    const float* __restrict__ src, const float* __restrict__ norm,
    bf16* __restrict__ dst, int n4) {
  const int i = blockIdx.x * 256 + threadIdx.x;
  if (i >= n4) return;
  const size_t f = (size_t)i * 4;
  f32x4 v = *(const f32x4*)(src + f);
  const float* np_ = norm + ((f >> 21) << 10) + (f & 1023);
#pragma unroll
  for (int c = 0; c < 4; c++) v[c] *= np_[c];
  *(bf16x4*)(dst + f) = __builtin_convertvector(v, bf16x4);
}

// ---------------------------------------------------------------------------
// Swizzled stage of a 128x64 bf16 tile into LDS (contiguous rows).
// ---------------------------------------------------------------------------
__device__ __forceinline__ void stage_sw(const bf16* __restrict__ g0, int ld,
                                         bf16* s0, int wave, int lane) {
  const int r = lane >> 3;
  const int c = (lane & 7) ^ r;
  const bf16* g = g0 + (size_t)(wave * 32 + r) * ld + c * 8;
  bf16* s = s0 + wave * 2048;
#pragma unroll
  for (int i = 0; i < 4; i++) {
    __builtin_amdgcn_global_load_lds(
        (const __attribute__((address_space(1))) void*)(uintptr_t)(g + (size_t)(i * 8) * ld),
        (__attribute__((address_space(3))) void*)(uintptr_t)(s + i * 512), 16, 0, 0);
  }
}

// ---------------------------------------------------------------------------
// GEMM1 (dual-B, gathered rows): H1 = A@B1^T, H3 = A@B3^T; G = silu(s*H1)*(s*H3).
// Block space: blockIdx.y = m-tile within chunk (global tile bt), blockIdx.x =
// n-tile (fractal uses 16 of 32). A rows come from xb via perm[] indirection.
// ---------------------------------------------------------------------------
__global__ __launch_bounds__(256, 2) void gemm1_kernel(
    const bf16* __restrict__ xb, const int* __restrict__ perm,
    const float* __restrict__ rms,
    const bf16* __restrict__ fw1, const bf16* __restrict__ fw3,
    const bf16* __restrict__ s1b, const bf16* __restrict__ s3b,
    const int* __restrict__ tileOff, bf16* __restrict__ G, int chunk) {
  const int bt = chunk * CT + blockIdx.y;
  int toff[9];
#pragma unroll
  for (int i = 0; i < 9; i++) toff[i] = tileOff[i];
  if (bt >= toff[8]) return;
  int e = 0;
#pragma unroll
  for (int i = 1; i < 8; i++) if (bt >= toff[i]) e = i;
  const bool isfr = (e < NFR);
  const int nt = isfr ? 16 : 32;
  if ((int)blockIdx.x >= nt) return;
  const bf16* B1 = isfr ? fw1 + (size_t)e * HF * DIM : s1b + (size_t)(e - NFR) * HS * DIM;
  const bf16* B3 = isfr ? fw3 + (size_t)e * HF * DIM : s3b + (size_t)(e - NFR) * HS * DIM;

  __shared__ __attribute__((aligned(16))) bf16 As[128 * 64];
  __shared__ __attribute__((aligned(16))) bf16 Bs1[128 * 64];
  __shared__ __attribute__((aligned(16))) bf16 Bs3[128 * 64];
  const int lane = threadIdx.x & 63, wave = threadIdx.x >> 6;
  const int wm = wave >> 1, wn = wave & 1;
  const int g0 = bt * 128;
  const int n0 = blockIdx.x * 128;

  // hoist gathered-token addresses for A staging (4 rows per lane)
  const int rA = lane >> 3;
  const int cA = (lane & 7) ^ rA;
  const bf16* Ag[4];
#pragma unroll
  for (int i = 0; i < 4; i++) {
    int tk = perm[g0 + wave * 32 + i * 8 + rA];
    if (tk < 0) tk = 0;
    Ag[i] = xb + (size_t)tk * DIM + cA * 8;
  }
  const bf16* B1b = B1 + (size_t)n0 * DIM;
  const bf16* B3b = B3 + (size_t)n0 * DIM;

  f32x4 acc1[4][4], acc3[4][4];
#pragma unroll
  for (int i = 0; i < 4; i++)
#pragma unroll
    for (int j = 0; j < 4; j++) {
      f32x4 z = {0.f, 0.f, 0.f, 0.f};
      acc1[i][j] = z; acc3[i][j] = z;
    }
  const int lr = lane & 15, lq = lane >> 4;
  bf16* Asw = As + wave * 2048;
  for (int k0 = 0; k0 < DIM; k0 += 64) {
#pragma unroll
    for (int i = 0; i < 4; i++) {
      __builtin_amdgcn_global_load_lds(
          (const __attribute__((address_space(1))) void*)(uintptr_t)(Ag[i] + k0),
          (__attribute__((address_space(3))) void*)(uintptr_t)(Asw + i * 512), 16, 0, 0);
    }
    stage_sw(B1b + k0, DIM, Bs1, wave, lane);
    stage_sw(B3b + k0, DIM, Bs3, wave, lane);
    __syncthreads();
#pragma unroll
    for (int ks = 0; ks < 2; ks++) {
      bf16x8 af[4], bf_[4], cf_[4];
#pragma unroll
      for (int mi = 0; mi < 4; mi++) {
        const int R = wm * 64 + mi * 16 + lr;
        af[mi] = *(const bf16x8*)(As + LDSOFF(R, ks * 4 + lq));
      }
#pragma unroll
      for (int ni = 0; ni < 4; ni++) {
        const int R = wn * 64 + ni * 16 + lr;
        bf_[ni] = *(const bf16x8*)(Bs1 + LDSOFF(R, ks * 4 + lq));
        cf_[ni] = *(const bf16x8*)(Bs3 + LDSOFF(R, ks * 4 + lq));
      }
#pragma unroll
      for (int mi = 0; mi < 4; mi++)
#pragma unroll
        for (int ni = 0; ni < 4; ni++) {
          acc1[mi][ni] = __builtin_amdgcn_mfma_f32_16x16x32_bf16(af[mi], bf_[ni], acc1[mi][ni], 0, 0, 0);
          acc3[mi][ni] = __builtin_amdgcn_mfma_f32_16x16x32_bf16(af[mi], cf_[ni], acc3[mi][ni], 0, 0, 0);
        }
    }
    __syncthreads();
  }
  // C/D layout col=lane&15, row=(lane>>4)*4+r  [m89/m91]
#pragma unroll
  for (int mi = 0; mi < 4; mi++) {
#pragma unroll
    for (int r = 0; r < 4; r++) {
      const int row_l = wm * 64 + mi * 16 + lq * 4 + r;
      float s = 1.0f;
      if (isfr) {
        int tok = perm[g0 + row_l];
        s = rms[tok < 0 ? 0 : tok];
      }
      bf16* Grow = G + (size_t)(blockIdx.y * 128 + row_l) * HS;
#pragma unroll
      for (int ni = 0; ni < 4; ni++) {
        const int col = n0 + wn * 64 + ni * 16 + lr;
        const float h1 = acc1[mi][ni][r] * s;
        const float h3 = acc3[mi][ni][r] * s;
        Grow[col] = (bf16)(h1 / (1.0f + __expf(-h1)) * h3);
      }
    }
  }
}

// ---------------------------------------------------------------------------
// GEMM2: Y = G @ W2^T (N=1024), scatter-add to out with fused epilogue:
//   fractal: out[tok] += cw*(gamma[col]*(rms[tok]*x*norm[col] + Y) + x)
//   plain:   out[tok] += cw*Y
// ---------------------------------------------------------------------------
__global__ __launch_bounds__(256, 2) void gemm2_kernel(
    const bf16* __restrict__ G, const int* __restrict__ perm,
    const float* __restrict__ cwg, const float* __restrict__ rms,
    const float* __restrict__ gamma_all, const float* __restrict__ norm_all,
    const float* __restrict__ x,
    const bf16* __restrict__ fw2, const bf16* __restrict__ s2b,
    const int* __restrict__ tileOff, float* __restrict__ out, int chunk) {
  const int bt = chunk * CT + blockIdx.y;
  int toff[9];
#pragma unroll
  for (int i = 0; i < 9; i++) toff[i] = tileOff[i];
  if (bt >= toff[8]) return;
  int e = 0;
#pragma unroll
  for (int i = 1; i < 8; i++) if (bt >= toff[i]) e = i;
  const bool isfr = (e < NFR);
  const int K = isfr ? HF : HS;
  const bf16* Bw = isfr ? fw2 + (size_t)e * DIM * HF : s2b + (size_t)(e - NFR) * DIM * HS;

  __shared__ __attribute__((aligned(16))) bf16 As[128 * 64];
  __shared__ __attribute__((aligned(16))) bf16 Bs[128 * 64];
  const int lane = threadIdx.x & 63, wave = threadIdx.x >> 6;
  const int wm = wave >> 1, wn = wave & 1;
  const int n0 = blockIdx.x * 128;
  f32x4 acc[4][4];
#pragma unroll
  for (int i = 0; i < 4; i++)
#pragma unroll
    for (int j = 0; j < 4; j++) { f32x4 z = {0.f, 0.f, 0.f, 0.f}; acc[i][j] = z; }
  const bf16* Ab = G + (size_t)(blockIdx.y * 128) * HS;   // chunk-local rows, stride 4096
  const bf16* Bb = Bw + (size_t)n0 * K;
  const int lr = lane & 15, lq = lane >> 4;
  for (int k0 = 0; k0 < K; k0 += 64) {
    stage_sw(Ab + k0, HS, As, wave, lane);
    stage_sw(Bb + k0, K, Bs, wave, lane);
    __syncthreads();
#pragma unroll
    for (int ks = 0; ks < 2; ks++) {
      bf16x8 af[4], bf_[4];
#pragma unroll
      for (int mi = 0; mi < 4; mi++) {
        const int R = wm * 64 + mi * 16 + lr;
        af[mi] = *(const bf16x8*)(As + LDSOFF(R, ks * 4 + lq));
      }
#pragma unroll
      for (int ni = 0; ni < 4; ni++) {
        const int R = wn * 64 + ni * 16 + lr;
        bf_[ni] = *(const bf16x8*)(Bs + LDSOFF(R, ks * 4 + lq));
      }
#pragma unroll
      for (int mi = 0; mi < 4; mi++)
#pragma unroll
        for (int ni = 0; ni < 4; ni++)
          acc[mi][ni] = __builtin_amdgcn_mfma_f32_16x16x32_bf16(af[mi], bf_[ni], acc[mi][ni], 0, 0, 0);
    }
    __syncthreads();
  }
#pragma unroll
  for (int mi = 0; mi < 4; mi++) {
#pragma unroll
    for (int r = 0; r < 4; r++) {
      const int row_l = wm * 64 + mi * 16 + lq * 4 + r;
      const int g_row = bt * 128 + row_l;
      const int tok = perm[g_row];
      if (tok < 0) continue;
      const float cw = cwg[g_row];
      const float rv = rms[tok];
#pragma unroll
      for (int ni = 0; ni < 4; ni++) {
        const int col = n0 + wn * 64 + ni * 16 + lr;
        const float a = acc[mi][ni][r];
        float res;
        if (isfr) {
          const float xvv = x[(size_t)tok * DIM + col];
          res = cw * (gamma_all[e * DIM + col] * (rv * xvv * norm_all[e * DIM + col] + a) + xvv);
        } else {
          res = cw * a;
        }
        atomicAdd(&out[(size_t)tok * DIM + col], res);
      }
    }
  }
}

// ---------------------------------------------------------------------------
extern "C" void kernel_launch(void* const* d_in, const int* in_sizes, int n_in,
                              void* d_out, int out_size, void* d_ws, size_t ws_size,
                              hipStream_t stream) {
  const float* x        = (const float*)d_in[0];
  const float* gate_w   = (const float*)d_in[1];
  const float* fr_norm  = (const float*)d_in[2];
  const float* fr_gamma = (const float*)d_in[3];
  const float* fr_w1    = (const float*)d_in[4];
  const float* fr_w2    = (const float*)d_in[5];
  const float* fr_w3    = (const float*)d_in[6];
  const float* sw_w1    = (const float*)d_in[7];
  const float* sw_w2    = (const float*)d_in[8];
  const float* sw_w3    = (const float*)d_in[9];
  float* out = (float*)d_out;

  char* ws = (char*)d_ws;                        // ~273 MB total (<= round-0 proven)
  bf16*  xb    = (bf16*)(ws);                    // 64 MB
  bf16*  fw1   = (bf16*)(ws + 67108864);         // 16 MB (fr_w1 * fr_norm)
  bf16*  fw3   = (bf16*)(ws + 83886080);         // 16 MB (fr_w3 * fr_norm)
  bf16*  fw2   = (bf16*)(ws + 100663296);        // 16 MB
  bf16*  s1b   = (bf16*)(ws + 117440512);        // 32 MB
  bf16*  s3b   = (bf16*)(ws + 150994944);        // 32 MB
  bf16*  s2b   = (bf16*)(ws + 184549376);        // 32 MB
  bf16*  G     = (bf16*)(ws + 218103808);        // 64 MB (8192 x 4096)
  float* rmsb  = (float*)(ws + 285212672);       // 128 KB
  int*   top2  = (int*)  (ws + 285343744);       // 128 KB
  float* c12   = (float*)(ws + 285474816);       // 256 KB
  int*   perm  = (int*)  (ws + 285736960);       // 260 KB
  float* cwg   = (float*)(ws + 286003200);       // 260 KB
  int*   cnt   = (int*)  (ws + 286269440);       // 32 B
  int*   cur   = (int*)  (ws + 286269472);       // 32 B
  int*   tileOff = (int*)(ws + 286269504);       // 36 B
  int*   rowOff  = (int*)(ws + 286269540);       // 32 B

  hipMemsetAsync(d_out, 0, (size_t)out_size * sizeof(float), stream);
  hipMemsetAsync(cnt, 0, 64, stream);            // cnt + cur
  hipMemsetAsync(perm, 0xFF, PADROWS * 4, stream);

  gate_kernel<<<B_TOK / 4, 256, 0, stream>>>(x, gate_w, xb, rmsb, top2, c12, cnt);
  offsets_kernel<<<1, 64, 0, stream>>>(cnt, tileOff, rowOff);
  assign_kernel<<<B_TOK / 256, 256, 0, stream>>>(top2, c12, rowOff, cur, perm, cwg);

  cvt_scaled_kernel<<<8192, 256, 0, stream>>>(fr_w1, fr_norm, fw1, 2097152);
  cvt_scaled_kernel<<<8192, 256, 0, stream>>>(fr_w3, fr_norm, fw3, 2097152);
  cvt_kernel<<<8192, 256, 0, stream>>>(fr_w2, fw2, 2097152);
  cvt_kernel<<<16384, 256, 0, stream>>>(sw_w1, s1b, 4194304);
  cvt_kernel<<<16384, 256, 0, stream>>>(sw_w3, s3b, 4194304);
  cvt_kernel<<<16384, 256, 0, stream>>>(sw_w2, s2b, 4194304);

  for (int c = 0; c < NCH; c++) {
    gemm1_kernel<<<dim3(32, CT), 256, 0, stream>>>(
        xb, perm, rmsb, fw1, fw3, s1b, s3b, tileOff, G, c);
    gemm2_kernel<<<dim3(8, CT), 256, 0, stream>>>(
        G, perm, cwg, rmsb, fr_gamma, fr_norm, x, fw2, s2b, tileOff, out, c);
  }
}